// Round 1
// baseline (92.927 us; speedup 1.0000x reference)
//
#include <hip/hip_runtime.h>
#include <hip/hip_bf16.h>

#define NROWS 8192
#define MCOLS 8192
#define DDIM  64
#define BT    128   // output tile edge

typedef __attribute__((ext_vector_type(8))) short bf16x8;
typedef __attribute__((ext_vector_type(4))) float f32x4;
typedef __attribute__((ext_vector_type(4))) unsigned short us4;

__device__ __forceinline__ unsigned short f2bf(float f) {
    union { __hip_bfloat16 b; unsigned short u; } cv;
    cv.b = __float2bfloat16(f);   // RNE
    return cv.u;
}
__device__ __forceinline__ float bf2f(unsigned short u) {
    union { unsigned int u; float f; } cv;
    cv.u = ((unsigned int)u) << 16;
    return cv.f;
}

// ARD-RBF via GEMM rewrite: sq = ||xs||^2 + ||ys||^2 - 2*xs.ys^T, out = os*exp(-0.5*sq)
// Cross term on MFMA with bf16 hi/lo split (3 products, lo*lo dropped) for f32-grade accuracy.
__global__ __launch_bounds__(256, 2)
void ard_rbf_kernel(const float* __restrict__ x, const float* __restrict__ y,
                    const float* __restrict__ log_l, const float* __restrict__ log_os,
                    float* __restrict__ out)
{
    // +8 bf16 pad (16B) per row: 144B row stride -> ~2-way LDS conflicts (free)
    __shared__ unsigned short Ah[BT][DDIM + 8], Al[BT][DDIM + 8];
    __shared__ unsigned short Bh[BT][DDIM + 8], Bl[BT][DDIM + 8];
    __shared__ float x2s[BT], y2s[BT];

    const int t    = threadIdx.x;
    const int bx   = blockIdx.x;      // col tile (over M / y)
    const int by   = blockIdx.y;      // row tile (over N / x)
    const int lane = t & 63;
    const int sub  = lane & 15;
    const int lg   = lane >> 4;

    // ---- Stage x-tile and y-tile: f32 -> bf16 hi/lo into LDS, norms via shuffle ----
    // 128 rows x 64 cols = 2048 float4; 256 threads x 8 iters.
    #pragma unroll
    for (int ab = 0; ab < 2; ++ab) {
        const float* __restrict__ src = ab ? y : x;
        unsigned short (*Hh)[DDIM + 8] = ab ? Bh : Ah;
        unsigned short (*Hl)[DDIM + 8] = ab ? Bl : Al;
        float* nrm = ab ? y2s : x2s;
        const int tb = (ab ? bx : by) * BT;
        #pragma unroll
        for (int i = 0; i < 8; ++i) {
            const int f   = i * 256 + t;       // flat float4 index in tile
            const int row = f >> 4;            // 16 float4 per row
            const int c4  = (f & 15) * 4;
            f32x4 v  = *reinterpret_cast<const f32x4*>(&src[(size_t)(tb + row) * DDIM + c4]);
            f32x4 ll = *reinterpret_cast<const f32x4*>(&log_l[c4]);
            us4 hh, lo;
            float psum = 0.0f;
            #pragma unroll
            for (int j = 0; j < 4; ++j) {
                float s = v[j] * __expf(-ll[j]);   // x / lengthscale
                psum += s * s;
                unsigned short hb = f2bf(s);
                hh[j] = hb;
                lo[j] = f2bf(s - bf2f(hb));
            }
            // sum across the 16 lanes that share this row
            psum += __shfl_xor(psum, 1);
            psum += __shfl_xor(psum, 2);
            psum += __shfl_xor(psum, 4);
            psum += __shfl_xor(psum, 8);
            *reinterpret_cast<us4*>(&Hh[row][c4]) = hh;
            *reinterpret_cast<us4*>(&Hl[row][c4]) = lo;
            if (sub == 0) nrm[row] = psum;
        }
    }
    __syncthreads();

    // ---- MFMA cross term: 4 waves in 2x2, each owns a 64x64 sub-tile ----
    const int wid = t >> 6;
    const int wr  = wid >> 1;
    const int wc  = wid & 1;

    f32x4 acc[4][4] = {};

    #pragma unroll
    for (int kk = 0; kk < 2; ++kk) {
        const int kb = kk * 32 + lg * 8;   // 8 consecutive k per lane-group
        bf16x8 ah[4], al[4];
        #pragma unroll
        for (int m = 0; m < 4; ++m) {
            const int r = wr * 64 + m * 16 + sub;
            ah[m] = *reinterpret_cast<const bf16x8*>(&Ah[r][kb]);
            al[m] = *reinterpret_cast<const bf16x8*>(&Al[r][kb]);
        }
        #pragma unroll
        for (int n = 0; n < 4; ++n) {
            const int c = wc * 64 + n * 16 + sub;
            bf16x8 bh = *reinterpret_cast<const bf16x8*>(&Bh[c][kb]);
            bf16x8 bl = *reinterpret_cast<const bf16x8*>(&Bl[c][kb]);
            #pragma unroll
            for (int m = 0; m < 4; ++m) {
                acc[m][n] = __builtin_amdgcn_mfma_f32_16x16x32_bf16(ah[m], bh, acc[m][n], 0, 0, 0);
                acc[m][n] = __builtin_amdgcn_mfma_f32_16x16x32_bf16(al[m], bh, acc[m][n], 0, 0, 0);
                acc[m][n] = __builtin_amdgcn_mfma_f32_16x16x32_bf16(ah[m], bl, acc[m][n], 0, 0, 0);
            }
        }
    }

    // ---- Epilogue: sq = max(x2 + y2 - 2c, 0); out = os * exp(-0.5*sq) ----
    const float os = __expf(log_os[0]);
    #pragma unroll
    for (int m = 0; m < 4; ++m) {
        const int rl0 = wr * 64 + m * 16 + lg * 4;   // C layout: row=(lane>>4)*4+j
        #pragma unroll
        for (int n = 0; n < 4; ++n) {
            const int cl = wc * 64 + n * 16 + sub;   // col = lane&15
            const float y2 = y2s[cl];
            const size_t g0 = (size_t)(by * BT + rl0) * MCOLS + (size_t)(bx * BT + cl);
            #pragma unroll
            for (int j = 0; j < 4; ++j) {
                float sq = fmaxf(x2s[rl0 + j] + y2 - 2.0f * acc[m][n][j], 0.0f);
                out[g0 + (size_t)j * MCOLS] = os * __expf(-0.5f * sq);
            }
        }
    }
}

extern "C" void kernel_launch(void* const* d_in, const int* in_sizes, int n_in,
                              void* d_out, int out_size, void* d_ws, size_t ws_size,
                              hipStream_t stream) {
    const float* x      = (const float*)d_in[0];
    const float* y      = (const float*)d_in[1];
    const float* log_l  = (const float*)d_in[2];
    const float* log_os = (const float*)d_in[3];
    float* out = (float*)d_out;

    dim3 grid(MCOLS / BT, NROWS / BT);   // 64 x 64 = 4096 blocks
    ard_rbf_kernel<<<grid, 256, 0, stream>>>(x, y, log_l, log_os, out);
}

// Round 2
// 76.903 us; speedup vs baseline: 1.2084x; 1.2084x over previous
//
#include <hip/hip_runtime.h>
#include <hip/hip_bf16.h>

#define NROWS 8192
#define MCOLS 8192
#define DDIM  64
#define BT    128   // output tile edge
#define TPB   512   // 8 waves, 2x4 wave grid

typedef __attribute__((ext_vector_type(8))) short bf16x8;
typedef __attribute__((ext_vector_type(4))) float f32x4;
typedef __attribute__((ext_vector_type(2))) unsigned int u32x2;

// ARD-RBF via GEMM rewrite: sq = ||xs||^2 + ||ys||^2 - 2*xs.ys^T, out = os*exp(-0.5*sq)
// Cross term on MFMA with bf16 hi/lo Dekker split (3 products, lo*lo dropped).
__global__ __launch_bounds__(TPB, 4)
void ard_rbf_kernel(const float* __restrict__ x, const float* __restrict__ y,
                    const float* __restrict__ log_l, const float* __restrict__ log_os,
                    float* __restrict__ out)
{
    // +8 bf16 pad (16B) per row: 144B row stride -> benign LDS conflicts
    __shared__ unsigned short Ah[BT][DDIM + 8], Al[BT][DDIM + 8];
    __shared__ unsigned short Bh[BT][DDIM + 8], Bl[BT][DDIM + 8];
    __shared__ float x2s[BT], y2s[BT];
    __shared__ float invl[DDIM];

    const int t    = threadIdx.x;
    const int bx   = blockIdx.x;      // col tile (over M / y)
    const int by   = blockIdx.y;      // row tile (over N / x)
    const int lane = t & 63;
    const int sub  = lane & 15;
    const int lg   = lane >> 4;

    // ---- Phase 0: inverse lengthscale, once per block ----
    if (t < DDIM) invl[t] = __expf(-log_l[t]);
    __syncthreads();

    // ---- Stage x-tile and y-tile: f32 -> bf16 hi/lo into LDS, norms via shuffle ----
    // Per tile: 128 rows x 16 float4 = 2048 float4; 512 threads x 4 iters.
    #pragma unroll
    for (int ab = 0; ab < 2; ++ab) {
        const float* __restrict__ src = ab ? y : x;
        unsigned short (*Hh)[DDIM + 8] = ab ? Bh : Ah;
        unsigned short (*Hl)[DDIM + 8] = ab ? Bl : Al;
        float* nrm = ab ? y2s : x2s;
        const int tb = (ab ? bx : by) * BT;
        #pragma unroll
        for (int i = 0; i < 4; ++i) {
            const int f   = i * TPB + t;       // flat float4 index in tile
            const int row = f >> 4;            // 16 float4 per row
            const int c4  = (f & 15) * 4;
            f32x4 v  = *reinterpret_cast<const f32x4*>(&src[(size_t)(tb + row) * DDIM + c4]);
            f32x4 il = *reinterpret_cast<const f32x4*>(&invl[c4]);

            float s0 = v[0] * il[0], s1 = v[1] * il[1];
            float s2 = v[2] * il[2], s3 = v[3] * il[3];
            float psum = s0 * s0 + s1 * s1 + s2 * s2 + s3 * s3;

            // Dekker split: hi = trunc16(f) (exact bf16), lo = f - hi (exact f32)
            unsigned int u0 = __float_as_uint(s0), u1 = __float_as_uint(s1);
            unsigned int u2 = __float_as_uint(s2), u3 = __float_as_uint(s3);
            float l0 = s0 - __uint_as_float(u0 & 0xFFFF0000u);
            float l1 = s1 - __uint_as_float(u1 & 0xFFFF0000u);
            float l2 = s2 - __uint_as_float(u2 & 0xFFFF0000u);
            float l3 = s3 - __uint_as_float(u3 & 0xFFFF0000u);
            unsigned int hp0 = (u0 >> 16) | (u1 & 0xFFFF0000u);
            unsigned int hp1 = (u2 >> 16) | (u3 & 0xFFFF0000u);
            // round-to-nearest (half-away) pack of lo
            unsigned int b0 = __float_as_uint(l0) + 0x8000u;
            unsigned int b1 = __float_as_uint(l1) + 0x8000u;
            unsigned int b2 = __float_as_uint(l2) + 0x8000u;
            unsigned int b3 = __float_as_uint(l3) + 0x8000u;
            unsigned int lp0 = (b0 >> 16) | (b1 & 0xFFFF0000u);
            unsigned int lp1 = (b2 >> 16) | (b3 & 0xFFFF0000u);

            // sum across the 16 lanes that share this row
            psum += __shfl_xor(psum, 1);
            psum += __shfl_xor(psum, 2);
            psum += __shfl_xor(psum, 4);
            psum += __shfl_xor(psum, 8);

            *reinterpret_cast<u32x2*>(&Hh[row][c4]) = u32x2{hp0, hp1};
            *reinterpret_cast<u32x2*>(&Hl[row][c4]) = u32x2{lp0, lp1};
            if (sub == 0) nrm[row] = psum;
        }
    }
    __syncthreads();

    // ---- MFMA cross term: 8 waves in 2x4, each owns a 64x32 sub-tile ----
    const int wid = t >> 6;
    const int wr  = wid >> 2;        // 0..1
    const int wc  = wid & 3;         // 0..3

    f32x4 acc[4][2] = {};

    #pragma unroll
    for (int kk = 0; kk < 2; ++kk) {
        const int kb = kk * 32 + lg * 8;   // 8 consecutive k per lane-group
        bf16x8 ah[4], al[4];
        #pragma unroll
        for (int m = 0; m < 4; ++m) {
            const int r = wr * 64 + m * 16 + sub;
            ah[m] = *reinterpret_cast<const bf16x8*>(&Ah[r][kb]);
            al[m] = *reinterpret_cast<const bf16x8*>(&Al[r][kb]);
        }
        #pragma unroll
        for (int n = 0; n < 2; ++n) {
            const int c = wc * 32 + n * 16 + sub;
            bf16x8 bh = *reinterpret_cast<const bf16x8*>(&Bh[c][kb]);
            bf16x8 bl = *reinterpret_cast<const bf16x8*>(&Bl[c][kb]);
            #pragma unroll
            for (int m = 0; m < 4; ++m) {
                acc[m][n] = __builtin_amdgcn_mfma_f32_16x16x32_bf16(ah[m], bh, acc[m][n], 0, 0, 0);
                acc[m][n] = __builtin_amdgcn_mfma_f32_16x16x32_bf16(al[m], bh, acc[m][n], 0, 0, 0);
                acc[m][n] = __builtin_amdgcn_mfma_f32_16x16x32_bf16(ah[m], bl, acc[m][n], 0, 0, 0);
            }
        }
    }

    // ---- Epilogue: sq = max(x2 + y2 - 2c, 0); out = exp(-0.5*sq + log_os) ----
    const float lnos = log_os[0];
    #pragma unroll
    for (int m = 0; m < 4; ++m) {
        const int rl0 = wr * 64 + m * 16 + lg * 4;   // C layout: row=(lane>>4)*4+j
        #pragma unroll
        for (int n = 0; n < 2; ++n) {
            const int cl = wc * 32 + n * 16 + sub;   // col = lane&15
            const float y2 = y2s[cl];
            const size_t g0 = (size_t)(by * BT + rl0) * MCOLS + (size_t)(bx * BT + cl);
            #pragma unroll
            for (int j = 0; j < 4; ++j) {
                float sq = fmaxf(x2s[rl0 + j] + y2 - 2.0f * acc[m][n][j], 0.0f);
                out[g0 + (size_t)j * MCOLS] = __expf(fmaf(-0.5f, sq, lnos));
            }
        }
    }
}

extern "C" void kernel_launch(void* const* d_in, const int* in_sizes, int n_in,
                              void* d_out, int out_size, void* d_ws, size_t ws_size,
                              hipStream_t stream) {
    const float* x      = (const float*)d_in[0];
    const float* y      = (const float*)d_in[1];
    const float* log_l  = (const float*)d_in[2];
    const float* log_os = (const float*)d_in[3];
    float* out = (float*)d_out;

    dim3 grid(MCOLS / BT, NROWS / BT);   // 64 x 64 = 4096 blocks
    ard_rbf_kernel<<<grid, TPB, 0, stream>>>(x, y, log_l, log_os, out);
}

// Round 3
// 61.059 us; speedup vs baseline: 1.5219x; 1.2595x over previous
//
#include <hip/hip_runtime.h>
#include <hip/hip_bf16.h>

#define NROWS 8192
#define MCOLS 8192
#define DDIM  64

typedef __attribute__((ext_vector_type(8))) short bf16x8;
typedef __attribute__((ext_vector_type(4))) float f32x4;
typedef __attribute__((ext_vector_type(2))) unsigned int u32x2;
typedef __attribute__((ext_vector_type(4))) unsigned int u32x4;

// ws layout (bytes):
//   Xh [512][2][64] x bf16x8 = 1 MiB @ 0        (x-hi fragments, MFMA order)
//   Xl                       = 1 MiB @ 1 MiB
//   Yh                       = 1 MiB @ 2 MiB
//   Yl                       = 1 MiB @ 3 MiB
//   x2 f32[8192] = 32 KiB            @ 4 MiB
//   y2 f32[8192] = 32 KiB            @ 4 MiB + 32 KiB
#define WS_NEED (4ull * 1024 * 1024 + 64 * 1024)

// ---------------- Kernel 1: pack x,y -> scaled bf16 hi/lo fragments + norms ----------------
// Fragment layout matches mfma_f32_16x16x32_bf16 operand order:
//   frag[rb][kk][lane][e] = v[rb*16 + (lane&15)][kk*32 + (lane>>4)*8 + e]
__global__ __launch_bounds__(256)
void pack_kernel(const float* __restrict__ x, const float* __restrict__ y,
                 const float* __restrict__ log_l, unsigned char* __restrict__ ws)
{
    const int t = threadIdx.x, lane = t & 63, wid = t >> 6;
    const int sub = lane & 15, lg = lane >> 4;
    const int gb  = blockIdx.x;             // 0..255
    const int isY = gb >> 7;                // first 128 blocks: x, rest: y
    const int rb  = ((gb & 127) << 2) | wid;  // 0..511

    const float* __restrict__ src = isY ? y : x;
    bf16x8* __restrict__ Ph = reinterpret_cast<bf16x8*>(ws + (isY ? (2u << 20) : 0u));
    bf16x8* __restrict__ Pl = reinterpret_cast<bf16x8*>(ws + (isY ? (3u << 20) : (1u << 20)));
    float*  __restrict__ nrm = reinterpret_cast<float*>(ws + (4u << 20) + (isY ? (32u << 10) : 0u));

    const int row = rb * 16 + sub;
    float psum = 0.0f;
    #pragma unroll
    for (int kk = 0; kk < 2; ++kk) {
        const int k0 = kk * 32 + lg * 8;
        f32x4 v0 = *reinterpret_cast<const f32x4*>(&src[(size_t)row * DDIM + k0]);
        f32x4 v1 = *reinterpret_cast<const f32x4*>(&src[(size_t)row * DDIM + k0 + 4]);
        f32x4 g0 = *reinterpret_cast<const f32x4*>(&log_l[k0]);
        f32x4 g1 = *reinterpret_cast<const f32x4*>(&log_l[k0 + 4]);
        float s[8];
        #pragma unroll
        for (int j = 0; j < 4; ++j) s[j]     = v0[j] * __expf(-g0[j]);
        #pragma unroll
        for (int j = 0; j < 4; ++j) s[4 + j] = v1[j] * __expf(-g1[j]);
        unsigned int hp[4], lp[4];
        #pragma unroll
        for (int p = 0; p < 4; ++p) {
            float a = s[2 * p], b = s[2 * p + 1];
            psum += a * a + b * b;
            unsigned int ua = __float_as_uint(a), ub = __float_as_uint(b);
            // Dekker split: hi = trunc16 (exact bf16), lo = f - hi (exact), RNE-ish pack of lo
            float la = a - __uint_as_float(ua & 0xFFFF0000u);
            float lb = b - __uint_as_float(ub & 0xFFFF0000u);
            hp[p] = (ua >> 16) | (ub & 0xFFFF0000u);
            lp[p] = ((__float_as_uint(la) + 0x8000u) >> 16) |
                    ((__float_as_uint(lb) + 0x8000u) & 0xFFFF0000u);
        }
        const int fi = (rb * 2 + kk) * 64 + lane;
        *reinterpret_cast<u32x4*>(&Ph[fi]) = u32x4{hp[0], hp[1], hp[2], hp[3]};
        *reinterpret_cast<u32x4*>(&Pl[fi]) = u32x4{lp[0], lp[1], lp[2], lp[3]};
    }
    // row sum: lanes sharing a row are {sub, sub+16, sub+32, sub+48}
    psum += __shfl_xor(psum, 16);
    psum += __shfl_xor(psum, 32);
    if (lg == 0) nrm[row] = psum;
}

// ---------------- Kernel 2: LDS-free MFMA + fused epilogue ----------------
// Each wave owns a 64x32 output tile; fragments loaded straight from ws (L2/L3-hot).
__global__ __launch_bounds__(256, 4)
void ard_rbf_main(const unsigned char* __restrict__ ws,
                  const float* __restrict__ log_os, float* __restrict__ out)
{
    const int t = threadIdx.x, lane = t & 63, wid = t >> 6;
    const int sub = lane & 15, lg = lane >> 4;
    const int bx = blockIdx.x;   // 0..127, 64-col tiles
    const int by = blockIdx.y;   // 0..63, 128-row tiles
    const int wr = wid >> 1, wc = wid & 1;

    const bf16x8* __restrict__ Xh = reinterpret_cast<const bf16x8*>(ws);
    const bf16x8* __restrict__ Xl = reinterpret_cast<const bf16x8*>(ws + (1u << 20));
    const bf16x8* __restrict__ Yh = reinterpret_cast<const bf16x8*>(ws + (2u << 20));
    const bf16x8* __restrict__ Yl = reinterpret_cast<const bf16x8*>(ws + (3u << 20));
    const float*  __restrict__ x2 = reinterpret_cast<const float*>(ws + (4u << 20));
    const float*  __restrict__ y2 = reinterpret_cast<const float*>(ws + (4u << 20) + (32u << 10));

    const int row0 = by * 128 + wr * 64;
    const int col0 = bx * 64 + wc * 32;
    const int rbA = row0 >> 4, rbB = col0 >> 4;

    f32x4 acc[4][2] = {};
    #pragma unroll
    for (int kk = 0; kk < 2; ++kk) {
        bf16x8 ah[4], al[4];
        #pragma unroll
        for (int m = 0; m < 4; ++m) {
            const int fi = ((rbA + m) * 2 + kk) * 64 + lane;
            ah[m] = Xh[fi];
            al[m] = Xl[fi];
        }
        #pragma unroll
        for (int n = 0; n < 2; ++n) {
            const int fj = ((rbB + n) * 2 + kk) * 64 + lane;
            bf16x8 bh = Yh[fj];
            bf16x8 bl = Yl[fj];
            #pragma unroll
            for (int m = 0; m < 4; ++m) {
                acc[m][n] = __builtin_amdgcn_mfma_f32_16x16x32_bf16(ah[m], bh, acc[m][n], 0, 0, 0);
                acc[m][n] = __builtin_amdgcn_mfma_f32_16x16x32_bf16(al[m], bh, acc[m][n], 0, 0, 0);
                acc[m][n] = __builtin_amdgcn_mfma_f32_16x16x32_bf16(ah[m], bl, acc[m][n], 0, 0, 0);
            }
        }
    }

    const float lnos = log_os[0];
    float y2v[2];
    #pragma unroll
    for (int n = 0; n < 2; ++n) y2v[n] = y2[col0 + n * 16 + sub];

    #pragma unroll
    for (int m = 0; m < 4; ++m) {
        const int rbase = row0 + m * 16 + lg * 4;   // C layout: row = (lane>>4)*4 + j
        float x2v[4];
        #pragma unroll
        for (int j = 0; j < 4; ++j) x2v[j] = x2[rbase + j];
        #pragma unroll
        for (int n = 0; n < 2; ++n) {
            const size_t g0 = (size_t)rbase * MCOLS + (size_t)(col0 + n * 16 + sub);
            #pragma unroll
            for (int j = 0; j < 4; ++j) {
                float sq = fmaxf(x2v[j] + y2v[n] - 2.0f * acc[m][n][j], 0.0f);
                out[g0 + (size_t)j * MCOLS] = __expf(fmaf(-0.5f, sq, lnos));
            }
        }
    }
}

// ---------------- Fallback (R2 kernel) if ws is too small ----------------
__global__ __launch_bounds__(512, 4)
void ard_rbf_fallback(const float* __restrict__ x, const float* __restrict__ y,
                      const float* __restrict__ log_l, const float* __restrict__ log_os,
                      float* __restrict__ out)
{
    __shared__ unsigned short Ah[128][DDIM + 8], Al[128][DDIM + 8];
    __shared__ unsigned short Bh[128][DDIM + 8], Bl[128][DDIM + 8];
    __shared__ float x2s[128], y2s[128];
    __shared__ float invl[DDIM];

    const int t = threadIdx.x;
    const int bx = blockIdx.x, by = blockIdx.y;
    const int lane = t & 63, sub = lane & 15, lg = lane >> 4;

    if (t < DDIM) invl[t] = __expf(-log_l[t]);
    __syncthreads();

    #pragma unroll
    for (int ab = 0; ab < 2; ++ab) {
        const float* __restrict__ src = ab ? y : x;
        unsigned short (*Hh)[DDIM + 8] = ab ? Bh : Ah;
        unsigned short (*Hl)[DDIM + 8] = ab ? Bl : Al;
        float* nrm = ab ? y2s : x2s;
        const int tb = (ab ? bx : by) * 128;
        #pragma unroll
        for (int i = 0; i < 4; ++i) {
            const int f = i * 512 + t;
            const int row = f >> 4;
            const int c4 = (f & 15) * 4;
            f32x4 v = *reinterpret_cast<const f32x4*>(&src[(size_t)(tb + row) * DDIM + c4]);
            f32x4 il = *reinterpret_cast<const f32x4*>(&invl[c4]);
            float s0 = v[0] * il[0], s1 = v[1] * il[1], s2 = v[2] * il[2], s3 = v[3] * il[3];
            float psum = s0 * s0 + s1 * s1 + s2 * s2 + s3 * s3;
            unsigned int u0 = __float_as_uint(s0), u1 = __float_as_uint(s1);
            unsigned int u2 = __float_as_uint(s2), u3 = __float_as_uint(s3);
            float l0 = s0 - __uint_as_float(u0 & 0xFFFF0000u);
            float l1 = s1 - __uint_as_float(u1 & 0xFFFF0000u);
            float l2 = s2 - __uint_as_float(u2 & 0xFFFF0000u);
            float l3 = s3 - __uint_as_float(u3 & 0xFFFF0000u);
            unsigned int hp0 = (u0 >> 16) | (u1 & 0xFFFF0000u);
            unsigned int hp1 = (u2 >> 16) | (u3 & 0xFFFF0000u);
            unsigned int lp0 = ((__float_as_uint(l0) + 0x8000u) >> 16) | ((__float_as_uint(l1) + 0x8000u) & 0xFFFF0000u);
            unsigned int lp1 = ((__float_as_uint(l2) + 0x8000u) >> 16) | ((__float_as_uint(l3) + 0x8000u) & 0xFFFF0000u);
            psum += __shfl_xor(psum, 1);
            psum += __shfl_xor(psum, 2);
            psum += __shfl_xor(psum, 4);
            psum += __shfl_xor(psum, 8);
            *reinterpret_cast<u32x2*>(&Hh[row][c4]) = u32x2{hp0, hp1};
            *reinterpret_cast<u32x2*>(&Hl[row][c4]) = u32x2{lp0, lp1};
            if (sub == 0) nrm[row] = psum;
        }
    }
    __syncthreads();

    const int wid = t >> 6;
    const int wr = wid >> 2, wc = wid & 3;
    f32x4 acc[4][2] = {};
    #pragma unroll
    for (int kk = 0; kk < 2; ++kk) {
        const int kb = kk * 32 + lg * 8;
        bf16x8 ah[4], al[4];
        #pragma unroll
        for (int m = 0; m < 4; ++m) {
            const int r = wr * 64 + m * 16 + sub;
            ah[m] = *reinterpret_cast<const bf16x8*>(&Ah[r][kb]);
            al[m] = *reinterpret_cast<const bf16x8*>(&Al[r][kb]);
        }
        #pragma unroll
        for (int n = 0; n < 2; ++n) {
            const int c = wc * 32 + n * 16 + sub;
            bf16x8 bh = *reinterpret_cast<const bf16x8*>(&Bh[c][kb]);
            bf16x8 bl = *reinterpret_cast<const bf16x8*>(&Bl[c][kb]);
            #pragma unroll
            for (int m = 0; m < 4; ++m) {
                acc[m][n] = __builtin_amdgcn_mfma_f32_16x16x32_bf16(ah[m], bh, acc[m][n], 0, 0, 0);
                acc[m][n] = __builtin_amdgcn_mfma_f32_16x16x32_bf16(al[m], bh, acc[m][n], 0, 0, 0);
                acc[m][n] = __builtin_amdgcn_mfma_f32_16x16x32_bf16(ah[m], bl, acc[m][n], 0, 0, 0);
            }
        }
    }
    const float lnos = log_os[0];
    #pragma unroll
    for (int m = 0; m < 4; ++m) {
        const int rl0 = wr * 64 + m * 16 + lg * 4;
        #pragma unroll
        for (int n = 0; n < 2; ++n) {
            const int cl = wc * 32 + n * 16 + sub;
            const float yy2 = y2s[cl];
            const size_t g0 = (size_t)(by * 128 + rl0) * MCOLS + (size_t)(bx * 128 + cl);
            #pragma unroll
            for (int j = 0; j < 4; ++j) {
                float sq = fmaxf(x2s[rl0 + j] + yy2 - 2.0f * acc[m][n][j], 0.0f);
                out[g0 + (size_t)j * MCOLS] = __expf(fmaf(-0.5f, sq, lnos));
            }
        }
    }
}

extern "C" void kernel_launch(void* const* d_in, const int* in_sizes, int n_in,
                              void* d_out, int out_size, void* d_ws, size_t ws_size,
                              hipStream_t stream) {
    const float* x      = (const float*)d_in[0];
    const float* y      = (const float*)d_in[1];
    const float* log_l  = (const float*)d_in[2];
    const float* log_os = (const float*)d_in[3];
    float* out = (float*)d_out;

    if (ws_size >= WS_NEED) {
        pack_kernel<<<256, 256, 0, stream>>>(x, y, log_l, (unsigned char*)d_ws);
        ard_rbf_main<<<dim3(128, 64), 256, 0, stream>>>((const unsigned char*)d_ws, log_os, out);
    } else {
        ard_rbf_fallback<<<dim3(64, 64), 512, 0, stream>>>(x, y, log_l, log_os, out);
    }
}